// Round 1
// baseline (547.116 us; speedup 1.0000x reference)
//
#include <hip/hip_runtime.h>

#define NA 384
#define NB 384
#define NBATCH 64
#define NEGV -1e20f

// One workgroup per batch element. Thread tid owns mu-column j = tid+1.
// Anti-diagonal wavefront: at step t, thread tid computes mu[i][j] with
// i = t - tid + 1 (when 1 <= i <= NA).
// Dependencies:
//   up   = mu[i-1][j]   : this thread's value from step t-1 (register)
//   left = mu[i][j-1]   : neighbor tid-1's value from step t-1 (LDS)
//   diag = mu[i-1][j-1] : neighbor's value from step t-2 == the `left` we
//                         read last step (register)
// pi[b][i-1][j-1] = softmax([up,left,diag] + W) * mask, and the +W shift
// cancels in softmax, so pi falls out of the same exponentials.
__global__ __launch_bounds__(NB) void dtw_mu_pi(
    const float* __restrict__ W, const float* __restrict__ mask,
    float* __restrict__ mu, float* __restrict__ pi)
{
    const int b = blockIdx.x;
    const int tid = threadIdx.x;                       // column j = tid+1
    const float* Wb = W    + (size_t)b * NA * NB + tid;
    const float* Mb = mask + (size_t)b * NA * NB + tid;
    float* mub = mu + (size_t)b * (NA + 1) * (NB + 1);
    float* pib = pi + ((size_t)b * NA * NB) * 3;

    __shared__ float buf[2][NB + 1];   // buf[x][0] = sentinel mu[i][0] = NEG

    // Boundary outputs: mu[b][0][:] and mu[b][:][0]
    mub[tid + 1] = NEGV;                               // row 0, cols 1..NB
    mub[(size_t)(tid + 1) * (NB + 1)] = NEGV;          // col 0, rows 1..NA
    if (tid == 0) {
        mub[0] = 0.0f;                                 // mu[0][0]
        buf[0][0] = NEGV;
        buf[1][0] = NEGV;
    }

    float up   = NEGV;                       // mu[0][j] for first active step
    float diag = (tid == 0) ? 0.0f : NEGV;   // mu[0][j-1]; (1,1) sees mu[0][0]=0
    __syncthreads();

    for (int t = 0; t < NA + NB - 1; ++t) {
        const int i = t - tid + 1;
        if (i >= 1 && i <= NA) {
            const float left = buf[(t & 1) ^ 1][tid];       // neighbor, step t-1
            const float w    = Wb[(size_t)(i - 1) * NB];    // alpha = 1
            const float m  = fmaxf(fmaxf(up, diag), left);
            const float eu = __expf(up   - m);
            const float el = __expf(left - m);
            const float ed = __expf(diag - m);
            const float s  = eu + el + ed;
            const float val = w + m + __logf(s);

            buf[t & 1][tid + 1] = val;
            mub[(size_t)i * (NB + 1) + tid + 1] = val;

            // pi[b][i-1][tid][:] = [eu, el, ed]/s * mask
            const float mk  = Mb[(size_t)(i - 1) * NB];
            const float inv = mk * __builtin_amdgcn_rcpf(s);
            const size_t o  = ((size_t)(i - 1) * NB + tid) * 3;
            pib[o + 0] = eu * inv;
            pib[o + 1] = el * inv;
            pib[o + 2] = ed * inv;

            up   = val;
            diag = left;
        }
        __syncthreads();
    }
}

extern "C" void kernel_launch(void* const* d_in, const int* in_sizes, int n_in,
                              void* d_out, int out_size, void* d_ws, size_t ws_size,
                              hipStream_t stream) {
    const float* W    = (const float*)d_in[0];
    const float* mask = (const float*)d_in[1];
    float* mu = (float*)d_out;
    float* pi = mu + (size_t)NBATCH * (NA + 1) * (NB + 1);

    hipLaunchKernelGGL(dtw_mu_pi, dim3(NBATCH), dim3(NB), 0, stream,
                       W, mask, mu, pi);
}

// Round 2
// 357.770 us; speedup vs baseline: 1.5292x; 1.5292x over previous
//
#include <hip/hip_runtime.h>

#define NA 384
#define NB 384
#define NBATCH 64
#define NEGV -1e20f
#define C 8            // steps per chunk
#define NWAVE 6        // 384 rows / 64 lanes

// Wave-panel DTW:
//   wave w owns rows r = 64w+1 .. 64w+64 (lane l -> row 64w+l+1)
//   lane l computes col j = s - l at local step s (skewed), s = 1..447
//   up   = mu[r-1][j]   : lane l-1's value from previous step  -> DPP wave_shr:1
//   left = mu[r][j-1]   : own previous value (register)
//   diag = mu[r-1][j-1] : previous step's `up` (register)
//   lane 0 takes `up` from the inter-wave boundary row in LDS (flag-synced)
// Outputs are staged per 8-step chunk as one float4 {pi_u,pi_l,pi_d,mu} per
// cell (ds_write_b128), then flushed with coalesced global stores; mask is
// applied at flush with coalesced loads.

typedef float f4 __attribute__((ext_vector_type(4)));
struct __attribute__((packed)) f4u { f4 v; };   // unaligned-capable float4

__global__ __launch_bounds__(384, 1) void dtw_mu_pi(
    const float* __restrict__ W, const float* __restrict__ mask,
    float* __restrict__ mu, float* __restrict__ pi)
{
    __shared__ float bound[NWAVE - 1][NB + 1];   // boundary rows mu[64w][1..384]
    __shared__ int   progress[NWAVE - 1];        // last boundary col published
    __shared__ f4    stage[NWAVE][64 * 9];       // per lane: 8 cells + 1 pad (144B stride)

    const int b   = blockIdx.x;
    const int tid = threadIdx.x;
    const int w   = tid >> 6;          // wave id 0..5
    const int l   = tid & 63;          // lane id
    const int rbase = w << 6;          // W-row of lane l is rbase+l

    const float* Wb = W    + (size_t)b * NA * NB;
    const float* Mb = mask + (size_t)b * NA * NB;
    float* mub = mu + (size_t)b * (NA + 1) * (NB + 1);
    float* pib = pi + (size_t)b * NA * NB * 3;

    // --- boundary outputs + flag init ---
    mub[tid + 1] = NEGV;                               // row 0, cols 1..384
    mub[(size_t)(tid + 1) * (NB + 1)] = NEGV;          // col 0, rows 1..384
    if (tid == 0) mub[0] = 0.0f;
    if (tid < NWAVE - 1) progress[tid] = 0;
    __syncthreads();

    const float* wrow = Wb + (size_t)(rbase + l) * NB;
    f4* st = &stage[w][0];

    float val  = NEGV;                                  // mu[r][j-1] (left)
    float diag = (rbase + l == 0) ? 0.0f : NEGV;        // mu[r-1][0]

    for (int s0 = 1; s0 < NB + 64; s0 += C) {           // s0 = 1,9,...,441
        // ---- W prefetch for this chunk (off the dependency chain) ----
        float wbuf[C];
        {
            const int k0 = s0 - l - 1;                  // first col (0-based)
            if (k0 >= 0 && k0 + C <= NB) {
                f4 a  = ((const f4u*)(wrow + k0))->v;
                f4 bb = ((const f4u*)(wrow + k0 + 4))->v;
                wbuf[0] = a.x; wbuf[1] = a.y; wbuf[2] = a.z; wbuf[3] = a.w;
                wbuf[4] = bb.x; wbuf[5] = bb.y; wbuf[6] = bb.z; wbuf[7] = bb.w;
            } else {
#pragma unroll
                for (int c = 0; c < C; ++c) {
                    const int col = k0 + c;
                    wbuf[c] = (col >= 0 && col < NB) ? wrow[col] : 0.0f;
                }
            }
        }

        // ---- wait for producer wave's boundary values ----
        if (w > 0 && s0 <= NB) {
            const int need = min(s0 + C - 1, NB);
            while (*(volatile int*)&progress[w - 1] < need)
                __builtin_amdgcn_s_sleep(2);
            __builtin_amdgcn_sched_barrier(0);
            asm volatile("" ::: "memory");
        }

        // ---- 8 wavefront steps ----
#pragma unroll
        for (int c = 0; c < C; ++c) {
            const int s = s0 + c;
            // up = lane l-1's previous val (whole-wave shift by 1)
            float upv = __int_as_float(__builtin_amdgcn_update_dpp(
                0, __float_as_int(val), 0x138 /*WAVE_SHR1*/, 0xF, 0xF, false));
            if (w > 0) {
                const float bnd = bound[w - 1][s <= NB ? s : NB];  // uniform read
                if (l == 0) upv = (s <= NB) ? bnd : NEGV;
            } else if (l == 0) {
                upv = NEGV;                      // row 0 interior is NEG
            }
            const int j = s - l;
            if (j >= 1 && j <= NB) {
                const float m  = fmaxf(fmaxf(upv, val), diag);
                const float eu = __expf(upv - m);
                const float el = __expf(val - m);
                const float ed = __expf(diag - m);
                const float ss = eu + el + ed;
                const float nv = wbuf[c] + m + __logf(ss);
                const float iv = __builtin_amdgcn_rcpf(ss);
                f4 cell; cell.x = eu * iv; cell.y = el * iv; cell.z = ed * iv; cell.w = nv;
                st[l * 9 + c] = cell;                         // ds_write_b128
                if (w < NWAVE - 1 && l == 63) bound[w][j] = nv;
                diag = upv;
                val  = nv;
            }
        }

        // ---- publish boundary progress (cols completed by lane 63) ----
        if (w < NWAVE - 1) {
            const int done = s0 + C - 1 - 63;
            if (done >= 1) {
                asm volatile("s_waitcnt lgkmcnt(0)" ::: "memory");
                if (l == 63) *(volatile int*)&progress[w] = done;
            }
        }

        // ---- coalesced flush of the chunk's 512 cells ----
        const int colbase = s0 - 1;            // pi col = colbase + cc - lrow
#pragma unroll
        for (int q = 0; q < 8; ++q) {
            const int cell = q * 64 + l;       // 0..511
            const int lrow = cell >> 3;        // staged lane-row 0..63
            const int cc   = cell & 7;         // staged step 0..7
            const int col  = colbase + cc - lrow;
            if (col >= 0 && col < NB) {
                const f4 v = st[lrow * 9 + cc];                 // ds_read_b128
                const float mk = Mb[(size_t)(rbase + lrow) * NB + col];
                const size_t g = ((size_t)(rbase + lrow) * NB + col) * 3;
                pib[g]     = v.x * mk;          // adjacent dwords -> dwordx3
                pib[g + 1] = v.y * mk;
                pib[g + 2] = v.z * mk;
                mub[(size_t)(rbase + lrow + 1) * (NB + 1) + (col + 1)] = v.w;
            }
        }
    }
}

extern "C" void kernel_launch(void* const* d_in, const int* in_sizes, int n_in,
                              void* d_out, int out_size, void* d_ws, size_t ws_size,
                              hipStream_t stream) {
    const float* W    = (const float*)d_in[0];
    const float* mask = (const float*)d_in[1];
    float* mu = (float*)d_out;
    float* pi = mu + (size_t)NBATCH * (NA + 1) * (NB + 1);

    hipLaunchKernelGGL(dtw_mu_pi, dim3(NBATCH), dim3(384), 0, stream,
                       W, mask, mu, pi);
}

// Round 3
// 284.758 us; speedup vs baseline: 1.9213x; 1.2564x over previous
//
#include <hip/hip_runtime.h>

#define NA 384
#define NB 384
#define NBATCH 64
#define NEGV -1e20f
#define C 8            // steps per chunk
#define NCW 6          // compute waves (rows 64w+1..64w+64)
#define TOT_CH 56      // chunks: s0 = 1 + 8k, k = 0..55 (covers s=1..448)
#define LOG2E 1.44269504088896340736f
#define LN2   0.69314718055994530942f

typedef float f4 __attribute__((ext_vector_type(4)));
struct __attribute__((packed)) f4u { f4 v; };

struct SharedT {
    f4    stage[2][NCW][64 * 9];   // ring: per lane 8 cells + pad (144B stride)
    float bound[NCW - 1][NB + 1];  // boundary rows mu'[64w][1..384] (log2 dom)
    int   progress[NCW - 1];       // last boundary col published by wave w
    int   computed[NCW];           // chunks staged by compute wave w
    int   drained[NCW][2];         // last chunk drained per (wave, ring slot)
};

__device__ __forceinline__ void loadW(float (&buf)[C], int s0,
                                      const float* __restrict__ wrow, int l) {
    const int k0 = s0 - l - 1;                  // first 0-based col this chunk
    if (k0 >= 0 && k0 + C <= NB) {
        f4 a = ((const f4u*)(wrow + k0))->v;
        f4 b = ((const f4u*)(wrow + k0 + 4))->v;
        buf[0] = a.x * LOG2E; buf[1] = a.y * LOG2E;
        buf[2] = a.z * LOG2E; buf[3] = a.w * LOG2E;
        buf[4] = b.x * LOG2E; buf[5] = b.y * LOG2E;
        buf[6] = b.z * LOG2E; buf[7] = b.w * LOG2E;
    } else {
#pragma unroll
        for (int c = 0; c < C; ++c) {
            const int col = k0 + c;
            buf[c] = (col >= 0 && col < NB) ? wrow[col] * LOG2E : 0.0f;
        }
    }
}

__device__ __forceinline__ void chunk_body(
    int k, int w, int l, const float* __restrict__ wrow,
    float (&wc)[C], float (&wn)[C], float& val, float& diag,
    SharedT& sh, f4* st)
{
    const int s0 = 1 + k * C;

    // prefetch next chunk's W (off the dependency chain)
    if (k + 1 < TOT_CH) loadW(wn, s0 + C, wrow, l);

    // ring slot free? (consumer must have drained chunk k-2 of this slot)
    if (k >= 2) {
        volatile int* dr = &sh.drained[w][k & 1];
        while (*dr < k - 2) __builtin_amdgcn_s_sleep(1);
        __builtin_amdgcn_sched_barrier(0);
        asm volatile("" ::: "memory");
    }

    // producer boundary ready?
    if (w > 0 && s0 <= NB) {
        const int need = (s0 + C - 1 < NB) ? s0 + C - 1 : NB;
        volatile int* pr = &sh.progress[w - 1];
        while (*pr < need) __builtin_amdgcn_s_sleep(1);
        __builtin_amdgcn_sched_barrier(0);
        asm volatile("" ::: "memory");
    }

    // prefetch boundary values for all 8 steps (uniform LDS reads, overlapped)
    float bnd[C];
    if (w > 0) {
#pragma unroll
        for (int c = 0; c < C; ++c) {
            const int s = s0 + c;
            bnd[c] = sh.bound[w - 1][s <= NB ? s : NB];
        }
    }

    // 8 relay steps
#pragma unroll
    for (int c = 0; c < C; ++c) {
        const int s = s0 + c;
        float upv = __int_as_float(__builtin_amdgcn_update_dpp(
            0, __float_as_int(val), 0x138 /*WAVE_SHR1*/, 0xF, 0xF, false));
        if (l == 0) upv = (w > 0 && s <= NB) ? bnd[c] : NEGV;
        const int j = s - l;
        if (j >= 1 && j <= NB) {
            const float m  = fmaxf(fmaxf(upv, val), diag);
            const float eu = exp2f(upv  - m);
            const float el = exp2f(val  - m);
            const float ed = exp2f(diag - m);
            const float ssum = eu + el + ed;
            const float nv = wc[c] + m + __log2f(ssum);
            const float iv = __builtin_amdgcn_rcpf(ssum);
            f4 cell; cell.x = eu * iv; cell.y = el * iv; cell.z = ed * iv; cell.w = nv;
            st[l * 9 + c] = cell;                          // ds_write_b128
            if (w < NCW - 1 && l == 63) sh.bound[w][j] = nv;
            diag = upv;
            val  = nv;
        }
    }

    // publish: staged data + boundary row are in LDS, then flags
    asm volatile("s_waitcnt lgkmcnt(0)" ::: "memory");
    if (l == 63) {
        if (w < NCW - 1) {
            const int done = s0 + C - 1 - 63;   // cols completed by lane 63
            if (done >= 1) *(volatile int*)&sh.progress[w] = done;
        }
        *(volatile int*)&sh.computed[w] = k + 1;
    }
}

__global__ __launch_bounds__(768, 1) void dtw_mu_pi(
    const float* __restrict__ W, const float* __restrict__ mask,
    float* __restrict__ mu, float* __restrict__ pi)
{
    __shared__ SharedT sh;

    const int b   = blockIdx.x;
    const int tid = threadIdx.x;
    const int w   = tid >> 6;          // wave 0..11
    const int l   = tid & 63;

    const float* Wb = W    + (size_t)b * NA * NB;
    const float* Mb = mask + (size_t)b * NA * NB;
    float* mub = mu + (size_t)b * (NA + 1) * (NB + 1);
    float* pib = pi + (size_t)b * NA * NB * 3;

    // boundary outputs + flag init
    if (tid < 384) {
        mub[tid + 1] = NEGV;                          // row 0, cols 1..384
        mub[(size_t)(tid + 1) * (NB + 1)] = NEGV;     // col 0, rows 1..384
    }
    if (tid == 0) mub[0] = 0.0f;
    if (tid < NCW - 1) sh.progress[tid] = 0;
    if (tid < NCW) sh.computed[tid] = 0;
    if (tid < 2 * NCW) sh.drained[tid >> 1][tid & 1] = -1;
    __syncthreads();

    if (w < NCW) {
        // ---------------- compute (relay) wave ----------------
        const int rbase = w << 6;
        const float* wrow = Wb + (size_t)(rbase + l) * NB;
        f4* st0 = &sh.stage[0][w][0];
        f4* st1 = &sh.stage[1][w][0];

        float val  = NEGV;                            // mu'[r][j-1]
        float diag = (rbase + l == 0) ? 0.0f : NEGV;  // mu'[r-1][0]
        float bufA[C], bufB[C];
        loadW(bufA, 1, wrow, l);

        for (int k = 0; k < TOT_CH; k += 2) {
            chunk_body(k,     w, l, wrow, bufA, bufB, val, diag, sh, st0);
            chunk_body(k + 1, w, l, wrow, bufB, bufA, val, diag, sh, st1);
        }
    } else {
        // ---------------- I/O (drain) wave ----------------
        const int cw    = w - NCW;                    // paired compute wave
        const int rbase = cw << 6;
        for (int k = 0; k < TOT_CH; ++k) {
            volatile int* cp = &sh.computed[cw];
            while (*cp < k + 1) __builtin_amdgcn_s_sleep(1);
            __builtin_amdgcn_sched_barrier(0);
            asm volatile("" ::: "memory");

            const f4* st = &sh.stage[k & 1][cw][0];
            const int colbase = k * C;
#pragma unroll
            for (int q = 0; q < 8; ++q) {
                const int cell = q * 64 + l;          // 0..511
                const int lrow = cell >> 3;           // staged lane-row
                const int cc   = cell & 7;            // staged step
                const int col  = colbase + cc - lrow;
                if (col >= 0 && col < NB) {
                    const f4 v = st[lrow * 9 + cc];   // ds_read_b128
                    const float mk = Mb[(size_t)(rbase + lrow) * NB + col];
                    const size_t g = ((size_t)(rbase + lrow) * NB + col) * 3;
                    pib[g]     = v.x * mk;            // -> dwordx3
                    pib[g + 1] = v.y * mk;
                    pib[g + 2] = v.z * mk;
                    mub[(size_t)(rbase + lrow + 1) * (NB + 1) + col + 1] = v.w * LN2;
                }
            }
            asm volatile("s_waitcnt lgkmcnt(0)" ::: "memory");
            if (l == 0) *(volatile int*)&sh.drained[cw][k & 1] = k;
        }
    }
}

extern "C" void kernel_launch(void* const* d_in, const int* in_sizes, int n_in,
                              void* d_out, int out_size, void* d_ws, size_t ws_size,
                              hipStream_t stream) {
    const float* W    = (const float*)d_in[0];
    const float* mask = (const float*)d_in[1];
    float* mu = (float*)d_out;
    float* pi = mu + (size_t)NBATCH * (NA + 1) * (NB + 1);

    hipLaunchKernelGGL(dtw_mu_pi, dim3(NBATCH), dim3(768), 0, stream,
                       W, mask, mu, pi);
}

// Round 4
// 262.094 us; speedup vs baseline: 2.0875x; 1.0865x over previous
//
#include <hip/hip_runtime.h>

#define NA 384
#define NB 384
#define NBATCH 64
#define NEGV -1e20f
#define C 8            // steps per chunk
#define NCW 6          // compute waves (rows 64w+1..64w+64)
#define TOT_CH 56      // chunks: s0 = 1 + 8k, k = 0..55 (covers s=1..448)
#define LOG2E 1.44269504088896340736f
#define LN2   0.69314718055994530942f

typedef float f4 __attribute__((ext_vector_type(4)));
struct __attribute__((packed)) f4u { f4 v; };

struct SharedT {
    f4    stage[2][NCW][64 * 9];   // ring: per lane 8 cells + pad (144B stride)
    float bound[NCW - 1][NB + 1];  // boundary rows mu'[64w][1..384] (log2 dom)
    int   progress[NCW - 1];       // last boundary col published by wave w
    int   computed[NCW];           // chunks staged by compute wave w
    int   drained[NCW][2];         // last chunk drained per (wave, ring slot)
};

__device__ __forceinline__ void loadW(float (&buf)[C], int s0,
                                      const float* __restrict__ wrow, int l) {
    const int k0 = s0 - l - 1;                  // first 0-based col this chunk
    if (k0 >= 0 && k0 + C <= NB) {
        f4 a = ((const f4u*)(wrow + k0))->v;
        f4 b = ((const f4u*)(wrow + k0 + 4))->v;
        buf[0] = a.x * LOG2E; buf[1] = a.y * LOG2E;
        buf[2] = a.z * LOG2E; buf[3] = a.w * LOG2E;
        buf[4] = b.x * LOG2E; buf[5] = b.y * LOG2E;
        buf[6] = b.z * LOG2E; buf[7] = b.w * LOG2E;
    } else {
#pragma unroll
        for (int c = 0; c < C; ++c) {
            const int col = k0 + c;
            buf[c] = (col >= 0 && col < NB) ? wrow[col] * LOG2E : 0.0f;
        }
    }
}

__device__ __forceinline__ void chunk_body(
    int k, int w, int l, const float* __restrict__ wrow,
    float (&wc)[C], float (&wn)[C], float& val, float& diag,
    SharedT& sh, f4* st)
{
    const int s0 = 1 + k * C;

    // prefetch next chunk's W (off the dependency chain)
    if (k + 1 < TOT_CH) loadW(wn, s0 + C, wrow, l);

    // ring slot free? (consumer must have drained chunk k-2 of this slot)
    if (k >= 2) {
        volatile int* dr = &sh.drained[w][k & 1];
        while (*dr < k - 2) __builtin_amdgcn_s_sleep(1);
        __builtin_amdgcn_sched_barrier(0);
        asm volatile("" ::: "memory");
    }

    // producer boundary ready?  (bare spin: this is the latency-critical relay)
    if (w > 0 && s0 <= NB) {
        const int need = (s0 + C - 1 < NB) ? s0 + C - 1 : NB;
        volatile int* pr = &sh.progress[w - 1];
        while (*pr < need) { }
        __builtin_amdgcn_sched_barrier(0);
        asm volatile("" ::: "memory");
    }

    // prefetch boundary values for all 8 steps (uniform LDS reads, overlapped)
    float bnd[C];
    if (w > 0) {
#pragma unroll
        for (int c = 0; c < C; ++c) {
            const int s = s0 + c;
            bnd[c] = sh.bound[w - 1][s <= NB ? s : NB];
        }
    }

    // 8 relay steps
#pragma unroll
    for (int c = 0; c < C; ++c) {
        const int s = s0 + c;
        float upv = __int_as_float(__builtin_amdgcn_update_dpp(
            0, __float_as_int(val), 0x138 /*WAVE_SHR1*/, 0xF, 0xF, false));
        if (l == 0) upv = (w > 0 && s <= NB) ? bnd[c] : NEGV;
        const int j = s - l;
        if (j >= 1 && j <= NB) {
            const float m  = fmaxf(fmaxf(upv, val), diag);   // -> v_max3_f32
            const float eu = exp2f(upv  - m);
            const float el = exp2f(val  - m);
            const float ed = exp2f(diag - m);
            const float ssum = eu + el + ed;
            const float nv = wc[c] + m + __log2f(ssum);
            const float iv = __builtin_amdgcn_rcpf(ssum);
            f4 cell; cell.x = eu * iv; cell.y = el * iv; cell.z = ed * iv; cell.w = nv;
            st[l * 9 + c] = cell;                          // ds_write_b128
            if (w < NCW - 1 && l == 63) sh.bound[w][j] = nv;
            diag = upv;
            val  = nv;
        }
    }

    // publish: staged data + boundary row are in LDS, then flags
    asm volatile("s_waitcnt lgkmcnt(0)" ::: "memory");
    if (l == 63) {
        if (w < NCW - 1) {
            const int done = s0 + C - 1 - 63;   // cols completed by lane 63
            if (done >= 1) *(volatile int*)&sh.progress[w] = done;
        }
        *(volatile int*)&sh.computed[w] = k + 1;
    }
}

__global__ __launch_bounds__(768, 1) void dtw_mu_pi(
    const float* __restrict__ W, const float* __restrict__ mask,
    float* __restrict__ mu, float* __restrict__ pi)
{
    __shared__ SharedT sh;

    const int b   = blockIdx.x;
    const int tid = threadIdx.x;
    const int w   = tid >> 6;          // wave 0..11
    const int l   = tid & 63;

    const float* Wb = W    + (size_t)b * NA * NB;
    const float* Mb = mask + (size_t)b * NA * NB;
    float* mub = mu + (size_t)b * (NA + 1) * (NB + 1);
    float* pib = pi + (size_t)b * NA * NB * 3;

    // boundary outputs + flag init
    if (tid < 384) {
        mub[tid + 1] = NEGV;                          // row 0, cols 1..384
        mub[(size_t)(tid + 1) * (NB + 1)] = NEGV;     // col 0, rows 1..384
    }
    if (tid == 0) mub[0] = 0.0f;
    if (tid < NCW - 1) sh.progress[tid] = 0;
    if (tid < NCW) sh.computed[tid] = 0;
    if (tid < 2 * NCW) sh.drained[tid >> 1][tid & 1] = -1;
    __syncthreads();

    if (w < NCW) {
        // ---------------- compute (relay) wave ----------------
        const int rbase = w << 6;
        const float* wrow = Wb + (size_t)(rbase + l) * NB;
        f4* st0 = &sh.stage[0][w][0];
        f4* st1 = &sh.stage[1][w][0];

        float val  = NEGV;                            // mu'[r][j-1]
        float diag = (rbase + l == 0) ? 0.0f : NEGV;  // mu'[r-1][0]
        float bufA[C], bufB[C];
        loadW(bufA, 1, wrow, l);

        for (int k = 0; k < TOT_CH; k += 2) {
            chunk_body(k,     w, l, wrow, bufA, bufB, val, diag, sh, st0);
            chunk_body(k + 1, w, l, wrow, bufB, bufA, val, diag, sh, st1);
        }
    } else {
        // ---------------- I/O (drain) wave ----------------
        const int cw    = w - NCW;                    // paired compute wave
        const int rbase = cw << 6;

        // mask prefetch: addresses are data-independent, issue a chunk ahead
        auto issue_mask = [&](int k, float (&mk)[C]) {
            const int colbase = k * C;
#pragma unroll
            for (int q = 0; q < 8; ++q) {
                const int cell = q * 64 + l;
                const int lrow = cell >> 3;
                const int cc   = cell & 7;
                int col = colbase + cc - lrow;
                col = col < 0 ? 0 : (col >= NB ? NB - 1 : col);
                mk[q] = Mb[(size_t)(rbase + lrow) * NB + col];
            }
        };
        auto wait_computed = [&](int k) {
            volatile int* cp = &sh.computed[cw];
            while (*cp < k + 1) __builtin_amdgcn_s_sleep(1);
            __builtin_amdgcn_sched_barrier(0);
            asm volatile("" ::: "memory");
        };
        auto drain = [&](int k, const float (&mk)[C]) {
            const f4* st = &sh.stage[k & 1][cw][0];
            const int colbase = k * C;
#pragma unroll
            for (int q = 0; q < 8; ++q) {
                const int cell = q * 64 + l;          // 0..511
                const int lrow = cell >> 3;           // staged lane-row
                const int cc   = cell & 7;            // staged step
                const int col  = colbase + cc - lrow;
                if (col >= 0 && col < NB) {
                    const f4 v = st[lrow * 9 + cc];   // ds_read_b128
                    const float m = mk[q];
                    const size_t g = ((size_t)(rbase + lrow) * NB + col) * 3;
                    pib[g]     = v.x * m;             // -> dwordx3
                    pib[g + 1] = v.y * m;
                    pib[g + 2] = v.z * m;
                    mub[(size_t)(rbase + lrow + 1) * (NB + 1) + col + 1] = v.w * LN2;
                }
            }
            asm volatile("s_waitcnt lgkmcnt(0)" ::: "memory");
            if (l == 0) *(volatile int*)&sh.drained[cw][k & 1] = k;
        };

        float mkA[C], mkB[C];
        issue_mask(0, mkA);
        for (int k = 0; k < TOT_CH; k += 2) {          // TOT_CH is even
            issue_mask(k + 1, mkB);                    // in flight during poll+drain k
            wait_computed(k);
            drain(k, mkA);
            if (k + 2 < TOT_CH) issue_mask(k + 2, mkA); // in flight during poll+drain k+1
            wait_computed(k + 1);
            drain(k + 1, mkB);
        }
    }
}

extern "C" void kernel_launch(void* const* d_in, const int* in_sizes, int n_in,
                              void* d_out, int out_size, void* d_ws, size_t ws_size,
                              hipStream_t stream) {
    const float* W    = (const float*)d_in[0];
    const float* mask = (const float*)d_in[1];
    float* mu = (float*)d_out;
    float* pi = mu + (size_t)NBATCH * (NA + 1) * (NB + 1);

    hipLaunchKernelGGL(dtw_mu_pi, dim3(NBATCH), dim3(768), 0, stream,
                       W, mask, mu, pi);
}

// Round 5
// 251.938 us; speedup vs baseline: 2.1716x; 1.0403x over previous
//
#include <hip/hip_runtime.h>

#define NA 384
#define NB 384
#define NBATCH 64
#define NEGV -1e20f
#define C 8            // steps per chunk
#define NCW 6          // compute waves (rows 64w+1..64w+64)
#define TOT_CH 56      // chunks: s0 = 1 + 8k, k = 0..55 (covers s=1..448)
#define LOG2E 1.44269504088896340736f
#define LN2   0.69314718055994530942f

typedef float f4 __attribute__((ext_vector_type(4)));
struct __attribute__((packed)) f4u { f4 v; };

struct SharedT {
    f4    stage[2][NCW][64 * 9];   // ring: per lane 8 cells + pad (144B stride)
    float bound[NCW - 1][NB + 1];  // boundary rows mu'[64w][1..384] (log2 dom)
    int   progress[NCW - 1];       // last boundary col published by wave w
    int   computed[NCW];           // chunks staged by compute wave w
    int   drained[NCW][2];         // last chunk drained per (wave, ring slot)
};

__device__ __forceinline__ void loadW(float (&buf)[C], int s0,
                                      const float* __restrict__ wrow, int l) {
    const int k0 = s0 - l - 1;                  // first 0-based col this chunk
    if (k0 >= 0 && k0 + C <= NB) {
        f4 a = ((const f4u*)(wrow + k0))->v;
        f4 b = ((const f4u*)(wrow + k0 + 4))->v;
        buf[0] = a.x * LOG2E; buf[1] = a.y * LOG2E;
        buf[2] = a.z * LOG2E; buf[3] = a.w * LOG2E;
        buf[4] = b.x * LOG2E; buf[5] = b.y * LOG2E;
        buf[6] = b.z * LOG2E; buf[7] = b.w * LOG2E;
    } else {
#pragma unroll
        for (int c = 0; c < C; ++c) {
            const int col = k0 + c;
            buf[c] = (col >= 0 && col < NB) ? wrow[col] * LOG2E : 0.0f;
        }
    }
}

// FULL: all lanes in j-range for all 8 steps (true for k in [8,47])
template<bool FULL>
__device__ __forceinline__ void chunk_body(
    int k, int w, int l, const float* __restrict__ wrow,
    float (&wc)[C], float (&wn)[C], float& val, float& diag,
    SharedT& sh, f4* st)
{
    const int s0 = 1 + k * C;

    // ring slot free? (consumer must have drained chunk k-2 of this slot)
    if (k >= 2) {
        volatile int* dr = &sh.drained[w][k & 1];
        while (*dr < k - 2) __builtin_amdgcn_s_sleep(1);
        __builtin_amdgcn_sched_barrier(0);
        asm volatile("" ::: "memory");
    }

    // producer boundary ready?  (bare spin: latency-critical relay edge)
    if (w > 0 && s0 <= NB) {
        const int need = (s0 + C - 1 < NB) ? s0 + C - 1 : NB;
        volatile int* pr = &sh.progress[w - 1];
        while (*pr < need) { }
        __builtin_amdgcn_sched_barrier(0);
        asm volatile("" ::: "memory");
    }

    // prefetch boundary values for all 8 steps (uniform LDS reads)
    float bnd[C];
    if (w > 0) {
#pragma unroll
        for (int c = 0; c < C; ++c) {
            const int s = s0 + c;
            bnd[c] = sh.bound[w - 1][s <= NB ? s : NB];
        }
    }

    // 8 relay steps
#pragma unroll
    for (int c = 0; c < C; ++c) {
        const int s = s0 + c;
        float upv = __int_as_float(__builtin_amdgcn_update_dpp(
            0, __float_as_int(val), 0x138 /*WAVE_SHR1*/, 0xF, 0xF, false));
        if (l == 0) upv = (w > 0 && s <= NB) ? bnd[c] : NEGV;
        const int j = s - l;
        if (FULL || (j >= 1 && j <= NB)) {
            const float m  = fmaxf(fmaxf(upv, val), diag);   // -> v_max3_f32
            const float eu = exp2f(upv  - m);
            const float el = exp2f(val  - m);
            const float ed = exp2f(diag - m);
            const float ssum = eu + el + ed;
            const float nv = wc[c] + m + __log2f(ssum);
            const float iv = __builtin_amdgcn_rcpf(ssum);
            f4 cell; cell.x = eu * iv; cell.y = el * iv; cell.z = ed * iv; cell.w = nv;
            st[l * 9 + c] = cell;                          // ds_write_b128
            if (w < NCW - 1 && l == 63) sh.bound[w][j] = nv;
            diag = upv;
            val  = nv;
        }
    }

    // publish: only DS ops are outstanding here (W prefetch moved below)
    asm volatile("s_waitcnt lgkmcnt(0)" ::: "memory");
    if (l == 63) {
        if (w < NCW - 1) {
            const int done = s0 + C - 1 - 63;   // cols completed by lane 63
            if (done >= 1) *(volatile int*)&sh.progress[w] = done;
        }
        *(volatile int*)&sh.computed[w] = k + 1;
    }

    // W prefetch for next chunk, AFTER publish (keeps its latency off the
    // flag path even if it lowers to flat_load counting lgkmcnt)
    if (k + 1 < TOT_CH) loadW(wn, s0 + C, wrow, l);
}

__global__ __launch_bounds__(768, 1) void dtw_mu_pi(
    const float* __restrict__ W, const float* __restrict__ mask,
    float* __restrict__ mu, float* __restrict__ pi)
{
    __shared__ SharedT sh;

    const int b   = blockIdx.x;
    const int tid = threadIdx.x;
    const int w   = tid >> 6;          // wave 0..11
    const int l   = tid & 63;

    const float* Wb = W    + (size_t)b * NA * NB;
    const float* Mb = mask + (size_t)b * NA * NB;
    float* mub = mu + (size_t)b * (NA + 1) * (NB + 1);
    float* pib = pi + (size_t)b * NA * NB * 3;

    // boundary outputs + flag init
    if (tid < 384) {
        mub[tid + 1] = NEGV;                          // row 0, cols 1..384
        mub[(size_t)(tid + 1) * (NB + 1)] = NEGV;     // col 0, rows 1..384
    }
    if (tid == 0) mub[0] = 0.0f;
    if (tid < NCW - 1) sh.progress[tid] = 0;
    if (tid < NCW) sh.computed[tid] = 0;
    if (tid < 2 * NCW) sh.drained[tid >> 1][tid & 1] = -1;
    __syncthreads();

    if (w < NCW) {
        // ---------------- compute (relay) wave ----------------
        __builtin_amdgcn_s_setprio(1);                // favor the critical path
        const int rbase = w << 6;
        const float* wrow = Wb + (size_t)(rbase + l) * NB;
        f4* st0 = &sh.stage[0][w][0];
        f4* st1 = &sh.stage[1][w][0];

        float val  = NEGV;                            // mu'[r][j-1]
        float diag = (rbase + l == 0) ? 0.0f : NEGV;  // mu'[r-1][0]
        float bufA[C], bufB[C];
        loadW(bufA, 1, wrow, l);

        for (int k = 0; k < 8; k += 2) {
            chunk_body<false>(k,     w, l, wrow, bufA, bufB, val, diag, sh, st0);
            chunk_body<false>(k + 1, w, l, wrow, bufB, bufA, val, diag, sh, st1);
        }
        for (int k = 8; k < 48; k += 2) {
            chunk_body<true>(k,     w, l, wrow, bufA, bufB, val, diag, sh, st0);
            chunk_body<true>(k + 1, w, l, wrow, bufB, bufA, val, diag, sh, st1);
        }
        for (int k = 48; k < TOT_CH; k += 2) {
            chunk_body<false>(k,     w, l, wrow, bufA, bufB, val, diag, sh, st0);
            chunk_body<false>(k + 1, w, l, wrow, bufB, bufA, val, diag, sh, st1);
        }
    } else {
        // ---------------- I/O (drain) wave ----------------
        const int cw    = w - NCW;                    // paired compute wave
        const int rbase = cw << 6;

        auto issue_mask = [&](int k, float (&mk)[C]) {
            const int colbase = k * C;
#pragma unroll
            for (int q = 0; q < 8; ++q) {
                const int cell = q * 64 + l;
                const int lrow = cell >> 3;
                const int cc   = cell & 7;
                int col = colbase + cc - lrow;
                col = col < 0 ? 0 : (col >= NB ? NB - 1 : col);
                mk[q] = Mb[(size_t)(rbase + lrow) * NB + col];
            }
        };

        auto process = [&](int k, float (&mk)[C]) {
            // wait for staged chunk
            volatile int* cp = &sh.computed[cw];
            while (*cp < k + 1) __builtin_amdgcn_s_sleep(1);
            __builtin_amdgcn_sched_barrier(0);
            asm volatile("" ::: "memory");

            // LDS -> registers, then release the ring slot IMMEDIATELY.
            const f4* st = &sh.stage[k & 1][cw][0];
            f4 v0, v1, v2, v3, v4, v5, v6, v7;
            {
                const int c0 = l, lr0 = c0 >> 3, cc0 = c0 & 7;
                const int c1 = 64 + l, lr1 = c1 >> 3, cc1 = c1 & 7;
                const int c2 = 128 + l, lr2 = c2 >> 3, cc2 = c2 & 7;
                const int c3 = 192 + l, lr3 = c3 >> 3, cc3 = c3 & 7;
                const int c4 = 256 + l, lr4 = c4 >> 3, cc4 = c4 & 7;
                const int c5 = 320 + l, lr5 = c5 >> 3, cc5 = c5 & 7;
                const int c6 = 384 + l, lr6 = c6 >> 3, cc6 = c6 & 7;
                const int c7 = 448 + l, lr7 = c7 >> 3, cc7 = c7 & 7;
                v0 = st[lr0 * 9 + cc0]; v1 = st[lr1 * 9 + cc1];
                v2 = st[lr2 * 9 + cc2]; v3 = st[lr3 * 9 + cc3];
                v4 = st[lr4 * 9 + cc4]; v5 = st[lr5 * 9 + cc5];
                v6 = st[lr6 * 9 + cc6]; v7 = st[lr7 * 9 + cc7];
            }
            asm volatile("s_waitcnt lgkmcnt(0)" ::: "memory");   // DS reads done
            if (l == 0) *(volatile int*)&sh.drained[cw][k & 1] = k;

            // now the slow part: mask-mul + global stores (off the flag path)
            const int colbase = k * C;
            const f4 vv[8] = {v0, v1, v2, v3, v4, v5, v6, v7};
#pragma unroll
            for (int q = 0; q < 8; ++q) {
                const int cell = q * 64 + l;
                const int lrow = cell >> 3;
                const int cc   = cell & 7;
                const int col  = colbase + cc - lrow;
                if (col >= 0 && col < NB) {
                    const float m = mk[q];
                    const size_t g = ((size_t)(rbase + lrow) * NB + col) * 3;
                    pib[g]     = vv[q].x * m;         // -> dwordx3
                    pib[g + 1] = vv[q].y * m;
                    pib[g + 2] = vv[q].z * m;
                    mub[(size_t)(rbase + lrow + 1) * (NB + 1) + col + 1] = vv[q].w * LN2;
                }
            }

            // mask prefetch for chunk k+2 (reuses this buffer), after stores
            if (k + 2 < TOT_CH) issue_mask(k + 2, mk);
        };

        float mkA[C], mkB[C];
        issue_mask(0, mkA);
        issue_mask(1, mkB);
        for (int k = 0; k < TOT_CH; k += 2) {          // TOT_CH is even
            process(k, mkA);
            process(k + 1, mkB);
        }
    }
}

extern "C" void kernel_launch(void* const* d_in, const int* in_sizes, int n_in,
                              void* d_out, int out_size, void* d_ws, size_t ws_size,
                              hipStream_t stream) {
    const float* W    = (const float*)d_in[0];
    const float* mask = (const float*)d_in[1];
    float* mu = (float*)d_out;
    float* pi = mu + (size_t)NBATCH * (NA + 1) * (NB + 1);

    hipLaunchKernelGGL(dtw_mu_pi, dim3(NBATCH), dim3(768), 0, stream,
                       W, mask, mu, pi);
}

// Round 6
// 173.700 us; speedup vs baseline: 3.1498x; 1.4504x over previous
//
#include <hip/hip_runtime.h>

#define NA 384
#define NB 384
#define NBATCH 64
#define NEGV -1e20f
#define C 8            // steps per chunk
#define NCW 6          // compute waves (rows 64w+1..64w+64)
#define TOT_CH 56      // chunks: s0 = 1 + 8k, k = 0..55
#define LOG2E 1.44269504088896340736f
#define LN2   0.69314718055994530942f

typedef float f4 __attribute__((ext_vector_type(4)));
struct __attribute__((packed)) F3 { float x, y, z; };   // 12B, align 4 -> dwordx3

struct SharedT {
    f4    stage[2][NCW][64 * 9];   // ring: per lane 8 cells + pad (144B stride)
    float wtile[NCW][512];         // W transpose buffer: [instr i*64 + lane]
    float bound[NCW - 1][NB + 1];  // boundary rows mu'[64w][1..384] (log2 dom)
    int   progress[NCW - 1];
    int   computed[NCW];
    int   drained[NCW][2];
};

// Skewed-coalesced W load for chunk kk: instruction i covers rows 8i..8i+7
// (8 lanes each) x 8 consecutive cols -> 8 cache lines per instruction
// (vs 64+ for the per-lane-row gather). Out-of-band cols clamped (values
// unused by the guarded relay).
__device__ __forceinline__ void loadW8(const float* __restrict__ Wb, int rbase,
                                       int kk, int l, float (&r)[8])
{
    const int rl = l >> 3, cc = l & 7;
    const int colb = 8 * kk + cc;          // col = colb - (8i + rl)
#pragma unroll
    for (int i = 0; i < 8; ++i) {
        const int row = 8 * i + rl;
        int col = colb - row;
        col = col < 0 ? 0 : (col > NB - 1 ? NB - 1 : col);
        r[i] = Wb[(size_t)(rbase + row) * NB + col];
    }
}

// FULL: all lanes in j-range for all 8 steps (k in [8,47])
template<bool FULL>
__device__ __forceinline__ void chunk_body(
    int k, int w, int l, const float* __restrict__ Wb, int rbase,
    float (&wreg)[8], float& val, float& diag, SharedT& sh)
{
    const int s0 = 1 + k * C;
    f4* st = &sh.stage[k & 1][w][0];
    float* wt = &sh.wtile[w][0];

    // ---- W(k): regs (coalesced layout) -> LDS -> regs (lane=row layout) ----
#pragma unroll
    for (int i = 0; i < 8; ++i) wt[i * 64 + l] = wreg[i];   // ds_write_b32 x8
    const int wb = (l >> 3) * 64 + ((l & 7) << 3);
    const f4 wlo = *(const f4*)(wt + wb);       // ds_read_b128 (in-order vs writes)
    const f4 whi = *(const f4*)(wt + wb + 4);

    // coalesced prefetch of W(k+1) into wreg (off the dependency chain)
    if (k + 1 < TOT_CH) loadW8(Wb, rbase, k + 1, l, wreg);

    // ---- ring slot free? (consumer drained chunk k-2 of this slot) ----
    if (k >= 2) {
        volatile int* dr = &sh.drained[w][k & 1];
        while (*dr < k - 2) __builtin_amdgcn_s_sleep(1);
        __builtin_amdgcn_sched_barrier(0);
        asm volatile("" ::: "memory");
    }

    // ---- producer boundary ready? (bare spin at prio 0) ----
    if (w > 0 && s0 <= NB) {
        const int need = (s0 + C - 1 < NB) ? s0 + C - 1 : NB;
        volatile int* pr = &sh.progress[w - 1];
        while (*pr < need) { }
        __builtin_amdgcn_sched_barrier(0);
        asm volatile("" ::: "memory");
    }

    // boundary values for all 8 steps (uniform LDS reads)
    float bnd[C];
    if (w > 0) {
#pragma unroll
        for (int c = 0; c < C; ++c) {
            const int s = s0 + c;
            bnd[c] = sh.bound[w - 1][s <= NB ? s : NB];
        }
    }

    float wc[C];
    wc[0] = wlo.x * LOG2E; wc[1] = wlo.y * LOG2E;
    wc[2] = wlo.z * LOG2E; wc[3] = wlo.w * LOG2E;
    wc[4] = whi.x * LOG2E; wc[5] = whi.y * LOG2E;
    wc[6] = whi.z * LOG2E; wc[7] = whi.w * LOG2E;

    __builtin_amdgcn_s_setprio(1);             // relay = critical path
    // ---- 8 relay steps ----
#pragma unroll
    for (int c = 0; c < C; ++c) {
        const int s = s0 + c;
        float upv = __int_as_float(__builtin_amdgcn_update_dpp(
            0, __float_as_int(val), 0x138 /*WAVE_SHR1*/, 0xF, 0xF, false));
        if (l == 0) upv = (w > 0 && s <= NB) ? bnd[c] : NEGV;
        const int j = s - l;
        if (FULL || (j >= 1 && j <= NB)) {
            const float m  = fmaxf(fmaxf(upv, val), diag);   // v_max3_f32
            const float eu = exp2f(upv  - m);
            const float el = exp2f(val  - m);
            const float ed = exp2f(diag - m);
            const float ssum = eu + el + ed;
            const float nv = wc[c] + m + __log2f(ssum);
            const float iv = __builtin_amdgcn_rcpf(ssum);
            f4 cell; cell.x = eu * iv; cell.y = el * iv; cell.z = ed * iv; cell.w = nv;
            st[l * 9 + c] = cell;                          // ds_write_b128
            if (w < NCW - 1 && l == 63) sh.bound[w][j] = nv;
            diag = upv;
            val  = nv;
        }
    }

    // publish (only DS ops outstanding on lgkm here)
    asm volatile("s_waitcnt lgkmcnt(0)" ::: "memory");
    if (l == 63) {
        if (w < NCW - 1) {
            const int done = s0 + C - 1 - 63;
            if (done >= 1) *(volatile int*)&sh.progress[w] = done;
        }
        *(volatile int*)&sh.computed[w] = k + 1;
    }
    __builtin_amdgcn_s_setprio(0);
}

__global__ __launch_bounds__(768, 1) void dtw_mu_pi(
    const float* __restrict__ W, const float* __restrict__ mask,
    float* __restrict__ mu, float* __restrict__ pi)
{
    __shared__ SharedT sh;

    const int b   = blockIdx.x;
    const int tid = threadIdx.x;
    const int w   = tid >> 6;          // wave 0..11
    const int l   = tid & 63;

    const float* Wb = W    + (size_t)b * NA * NB;
    const float* Mb = mask + (size_t)b * NA * NB;
    float* mub = mu + (size_t)b * (NA + 1) * (NB + 1);
    float* pib = pi + (size_t)b * NA * NB * 3;

    if (tid < 384) {
        mub[tid + 1] = NEGV;                          // row 0, cols 1..384
        mub[(size_t)(tid + 1) * (NB + 1)] = NEGV;     // col 0, rows 1..384
    }
    if (tid == 0) mub[0] = 0.0f;
    if (tid < NCW - 1) sh.progress[tid] = 0;
    if (tid < NCW) sh.computed[tid] = 0;
    if (tid < 2 * NCW) sh.drained[tid >> 1][tid & 1] = -1;
    __syncthreads();

    if (w < NCW) {
        // ---------------- compute (relay) wave ----------------
        const int rbase = w << 6;
        float val  = NEGV;                            // mu'[r][j-1]
        float diag = (rbase + l == 0) ? 0.0f : NEGV;  // mu'[r-1][0]
        float wreg[8];
        loadW8(Wb, rbase, 0, l, wreg);

        for (int k = 0; k < 8; ++k)
            chunk_body<false>(k, w, l, Wb, rbase, wreg, val, diag, sh);
        for (int k = 8; k < 48; ++k)
            chunk_body<true>(k, w, l, Wb, rbase, wreg, val, diag, sh);
        for (int k = 48; k < TOT_CH; ++k)
            chunk_body<false>(k, w, l, Wb, rbase, wreg, val, diag, sh);
    } else {
        // ---------------- I/O (drain) wave ----------------
        const int cw    = w - NCW;
        const int rbase = cw << 6;

        auto issue_mask = [&](int k, float (&mk)[C]) {
            const int colbase = k * C;
#pragma unroll
            for (int q = 0; q < 8; ++q) {
                const int cell = q * 64 + l;
                const int lrow = cell >> 3;
                const int cc   = cell & 7;
                int col = colbase + cc - lrow;
                col = col < 0 ? 0 : (col >= NB ? NB - 1 : col);
                mk[q] = Mb[(size_t)(rbase + lrow) * NB + col];
            }
        };

        auto process = [&](auto FULLC, int k, float (&mk)[C]) {
            constexpr bool FULL = FULLC.value;
            volatile int* cp = &sh.computed[cw];
            while (*cp < k + 1) __builtin_amdgcn_s_sleep(1);
            __builtin_amdgcn_sched_barrier(0);
            asm volatile("" ::: "memory");

            // LDS -> regs, release ring slot immediately
            const f4* st = &sh.stage[k & 1][cw][0];
            f4 v0, v1, v2, v3, v4, v5, v6, v7;
            {
                const int lr = l >> 3, cc = l & 7;      // q=0 cell
                v0 = st[lr * 9 + cc];
                v1 = st[(lr + 8)  * 9 + cc];
                v2 = st[(lr + 16) * 9 + cc];
                v3 = st[(lr + 24) * 9 + cc];
                v4 = st[(lr + 32) * 9 + cc];
                v5 = st[(lr + 40) * 9 + cc];
                v6 = st[(lr + 48) * 9 + cc];
                v7 = st[(lr + 56) * 9 + cc];
            }
            asm volatile("s_waitcnt lgkmcnt(0)" ::: "memory");
            if (l == 0) *(volatile int*)&sh.drained[cw][k & 1] = k;

            const int colbase = k * C;
            const f4 vv[8] = {v0, v1, v2, v3, v4, v5, v6, v7};
#pragma unroll
            for (int q = 0; q < 8; ++q) {
                const int cell = q * 64 + l;
                const int lrow = cell >> 3;
                const int cc   = cell & 7;
                const int col  = colbase + cc - lrow;
                if (FULL || (col >= 0 && col < NB)) {
                    const float m = mk[q];
                    const size_t g = ((size_t)(rbase + lrow) * NB + col) * 3;
                    F3 p3; p3.x = vv[q].x * m; p3.y = vv[q].y * m; p3.z = vv[q].z * m;
                    *(F3*)(pib + g) = p3;                 // global_store_dwordx3
                    mub[(size_t)(rbase + lrow + 1) * (NB + 1) + col + 1] = vv[q].w * LN2;
                }
            }
            if (k + 2 < TOT_CH) issue_mask(k + 2, mk);
        };

        float mkA[C], mkB[C];
        issue_mask(0, mkA);
        issue_mask(1, mkB);
        constexpr auto FT = std::integral_constant<bool, false>{};
        constexpr auto TT = std::integral_constant<bool, true>{};
        for (int k = 0; k < 8; k += 2) {
            process(FT, k, mkA); process(FT, k + 1, mkB);
        }
        for (int k = 8; k < 48; k += 2) {
            process(TT, k, mkA); process(TT, k + 1, mkB);
        }
        for (int k = 48; k < TOT_CH; k += 2) {
            process(FT, k, mkA); process(FT, k + 1, mkB);
        }
    }
}

extern "C" void kernel_launch(void* const* d_in, const int* in_sizes, int n_in,
                              void* d_out, int out_size, void* d_ws, size_t ws_size,
                              hipStream_t stream) {
    const float* W    = (const float*)d_in[0];
    const float* mask = (const float*)d_in[1];
    float* mu = (float*)d_out;
    float* pi = mu + (size_t)NBATCH * (NA + 1) * (NB + 1);

    hipLaunchKernelGGL(dtw_mu_pi, dim3(NBATCH), dim3(768), 0, stream,
                       W, mask, mu, pi);
}

// Round 7
// 164.313 us; speedup vs baseline: 3.3297x; 1.0571x over previous
//
#include <hip/hip_runtime.h>

#define NA 384
#define NB 384
#define NBATCH 64
#define NEGV -1e20f
#define C 8            // steps per chunk
#define NCW 6          // compute waves (rows 64w+1..64w+64)
#define TOT_CH 56      // chunks: s0 = 1 + 8k, k = 0..55
#define WPITCH 68      // wtile row pitch (floats); keeps b128 align, spreads banks
#define LOG2E 1.44269504088896340736f
#define LN2   0.69314718055994530942f

typedef float f4 __attribute__((ext_vector_type(4)));

struct alignas(16) SharedT {
    float stage[2][NCW][64 * 9];      // mu staging ring (log2 domain)
    float wtile[2][NCW][8 * WPITCH];  // transposed W ring (written by IO wave)
    float bound[NCW - 1][NB + 1];     // boundary rows mu'[64w][1..384]
    int   progress[NCW - 1];
    int   computed[NCW];
    int   drained[NCW][2];
    int   wready[NCW];                // chunks whose wtile is ready
};

// Skewed-coalesced W load for chunk kk: instr i covers rows 8i..8i+7 x 8
// consecutive cols (8 cache lines/instr). Element: lane l -> W[row][col],
// row = 8i + (l>>3), col = 8kk + (l&7) - row (clamped; clamped values unused).
__device__ __forceinline__ void loadW8(const float* __restrict__ Wb, int rbase,
                                       int kk, int l, float (&r)[8])
{
    const int rl = l >> 3, cc = l & 7;
    const int colb = 8 * kk + cc;
#pragma unroll
    for (int i = 0; i < 8; ++i) {
        const int row = 8 * i + rl;
        int col = colb - row;
        col = col < 0 ? 0 : (col > NB - 1 ? NB - 1 : col);
        r[i] = Wb[(size_t)(rbase + row) * NB + col];
    }
}

// ---------------- compute (relay) chunk ----------------
template<bool FULL>
__device__ __forceinline__ void chunk_body(int k, int w, int l,
                                           float& val, float& diag, SharedT& sh)
{
    const int s0 = 1 + k * C;

    // W tile ready? (IO wave produces; rarely blocks after prologue)
    {
        volatile int* wr = &sh.wready[w];
        while (*wr < k + 1) { }
        __builtin_amdgcn_sched_barrier(0);
        asm volatile("" ::: "memory");
    }
    // lane l needs W[row l][8k + c - l], c=0..7 -> 8 consecutive wtile floats
    const float* wt = &sh.wtile[k & 1][w][0];
    const int wb = (l >> 3) * WPITCH + (l & 7) * 8;
    const f4 wlo = *(const f4*)(wt + wb);
    const f4 whi = *(const f4*)(wt + wb + 4);

    // stage ring slot free?
    if (k >= 2) {
        volatile int* dr = &sh.drained[w][k & 1];
        while (*dr < k - 2) __builtin_amdgcn_s_sleep(1);
        __builtin_amdgcn_sched_barrier(0);
        asm volatile("" ::: "memory");
    }
    // producer boundary ready? (bare spin: latency-critical relay edge)
    if (w > 0 && s0 <= NB) {
        const int need = (s0 + C - 1 < NB) ? s0 + C - 1 : NB;
        volatile int* pr = &sh.progress[w - 1];
        while (*pr < need) { }
        __builtin_amdgcn_sched_barrier(0);
        asm volatile("" ::: "memory");
    }
    float bnd[C];
    if (w > 0) {
#pragma unroll
        for (int c = 0; c < C; ++c) {
            const int s = s0 + c;
            bnd[c] = sh.bound[w - 1][s <= NB ? s : NB];
        }
    }
    float wc[C];
    wc[0] = wlo.x * LOG2E; wc[1] = wlo.y * LOG2E;
    wc[2] = wlo.z * LOG2E; wc[3] = wlo.w * LOG2E;
    wc[4] = whi.x * LOG2E; wc[5] = whi.y * LOG2E;
    wc[6] = whi.z * LOG2E; wc[7] = whi.w * LOG2E;

    float* st = &sh.stage[k & 1][w][0];
    __builtin_amdgcn_s_setprio(1);
#pragma unroll
    for (int c = 0; c < C; ++c) {
        const int s = s0 + c;
        float upv = __int_as_float(__builtin_amdgcn_update_dpp(
            0, __float_as_int(val), 0x138 /*WAVE_SHR1*/, 0xF, 0xF, false));
        if (l == 0) upv = (w > 0 && s <= NB) ? bnd[c] : NEGV;
        const int j = s - l;
        if (FULL || (j >= 1 && j <= NB)) {
            const float m  = fmaxf(fmaxf(upv, val), diag);   // v_max3_f32
            const float eu = exp2f(upv  - m);
            const float el = exp2f(val  - m);
            const float ed = exp2f(diag - m);
            const float nv = wc[c] + m + __log2f(eu + el + ed);
            st[l * 9 + c] = nv;                              // ds_write_b32
            if (w < NCW - 1 && l == 63) sh.bound[w][j] = nv;
            diag = upv;
            val  = nv;
        }
    }
    asm volatile("s_waitcnt lgkmcnt(0)" ::: "memory");       // DS only here
    if (l == 63) {
        if (w < NCW - 1) {
            const int done = s0 + C - 1 - 63;
            if (done >= 1) *(volatile int*)&sh.progress[w] = done;
        }
        *(volatile int*)&sh.computed[w] = k + 1;
    }
    __builtin_amdgcn_s_setprio(0);
}

// ---------------- IO iteration: drain mu, feed W ----------------
template<bool FULL>
__device__ __forceinline__ void io_iter(int k, int cw, int l,
        const float* __restrict__ Wb, int rbase, float* __restrict__ mub,
        SharedT& sh)
{
    float wreg[8];
    const bool prep = (k + 2 < TOT_CH);
    if (prep) loadW8(Wb, rbase, k + 2, l, wreg);   // issue early, latency hides

    volatile int* cp = &sh.computed[cw];
    while (*cp < k + 1) __builtin_amdgcn_s_sleep(1);
    __builtin_amdgcn_sched_barrier(0);
    asm volatile("" ::: "memory");

    // stage -> regs (transposed), release ring slot immediately
    const float* st = &sh.stage[k & 1][cw][0];
    float v[8];
    const int lr = l >> 3, cc = l & 7;
#pragma unroll
    for (int q = 0; q < 8; ++q) v[q] = st[(lr + 8 * q) * 9 + cc];
    asm volatile("s_waitcnt lgkmcnt(0)" ::: "memory");
    if (l == 0) *(volatile int*)&sh.drained[cw][k & 1] = k;

    // W(k+2) -> wtile slot k&1 (compute consumed wc(k) already), publish
    if (prep) {
        float* wt = &sh.wtile[k & 1][cw][0];
#pragma unroll
        for (int i = 0; i < 8; ++i) wt[i * WPITCH + l] = wreg[i];
        asm volatile("s_waitcnt lgkmcnt(0)" ::: "memory");
        if (l == 0) *(volatile int*)&sh.wready[cw] = k + 3;
    }

    // mu stores LAST (latency off all flag paths); row-segments of 8 cols
    const int colbase = k * C;
#pragma unroll
    for (int q = 0; q < 8; ++q) {
        const int lrow = lr + 8 * q;
        const int col  = colbase + cc - lrow;
        if (FULL || (col >= 0 && col < NB))
            mub[(size_t)(rbase + lrow + 1) * (NB + 1) + col + 1] = v[q] * LN2;
    }
}

__global__ __launch_bounds__(768, 1) void dtw_mu(const float* __restrict__ W,
                                                 float* __restrict__ mu)
{
    __shared__ SharedT sh;
    const int b = blockIdx.x, tid = threadIdx.x;
    const int w = tid >> 6, l = tid & 63;
    const float* Wb = W + (size_t)b * NA * NB;
    float* mub = mu + (size_t)b * (NA + 1) * (NB + 1);

    if (tid < 384) {
        mub[tid + 1] = NEGV;                          // row 0, cols 1..384
        mub[(size_t)(tid + 1) * (NB + 1)] = NEGV;     // col 0, rows 1..384
    }
    if (tid == 0) mub[0] = 0.0f;
    if (tid < NCW - 1) sh.progress[tid] = 0;
    if (tid < NCW) { sh.computed[tid] = 0; sh.wready[tid] = 0; }
    if (tid < 2 * NCW) sh.drained[tid >> 1][tid & 1] = -1;
    __syncthreads();

    if (w < NCW) {
        const int rbase = w << 6;
        float val  = NEGV;                            // mu'[r][j-1]
        float diag = (rbase + l == 0) ? 0.0f : NEGV;  // mu'[r-1][0]
        for (int k = 0; k < 8; ++k)       chunk_body<false>(k, w, l, val, diag, sh);
        for (int k = 8; k < 48; ++k)      chunk_body<true >(k, w, l, val, diag, sh);
        for (int k = 48; k < TOT_CH; ++k) chunk_body<false>(k, w, l, val, diag, sh);
    } else {
        const int cw = w - NCW, rbase = cw << 6;
        float wreg[8];
        loadW8(Wb, rbase, 0, l, wreg);
        {
            float* wt = &sh.wtile[0][cw][0];
#pragma unroll
            for (int i = 0; i < 8; ++i) wt[i * WPITCH + l] = wreg[i];
        }
        loadW8(Wb, rbase, 1, l, wreg);
        {
            float* wt = &sh.wtile[1][cw][0];
#pragma unroll
            for (int i = 0; i < 8; ++i) wt[i * WPITCH + l] = wreg[i];
        }
        asm volatile("s_waitcnt lgkmcnt(0)" ::: "memory");
        if (l == 0) *(volatile int*)&sh.wready[cw] = 2;

        for (int k = 0; k < 8; ++k)       io_iter<false>(k, cw, l, Wb, rbase, mub, sh);
        for (int k = 8; k < 48; ++k)      io_iter<true >(k, cw, l, Wb, rbase, mub, sh);
        for (int k = 48; k < TOT_CH; ++k) io_iter<false>(k, cw, l, Wb, rbase, mub, sh);
    }
}

// ---------------- pass 2: pi = exp(x + W - mu_ij) * mask ----------------
// pi[b,ii,jj,m]: u=mu[b][ii][jj+1], lf=mu[b][ii+1][jj], dg=mu[b][ii][jj],
// mij=mu[b][ii+1][jj+1]. 4 cells/thread, all loads/stores 16B coalesced.
__global__ __launch_bounds__(256) void dtw_pi(const float* __restrict__ W,
        const float* __restrict__ mask, const float* __restrict__ mu,
        float* __restrict__ pi)
{
    const long long idx = ((long long)blockIdx.x * 256 + threadIdx.x) * 4;
    const int rr = (int)(idx / NB);          // b*NA + ii
    const int jj = (int)(idx - (long long)rr * NB);
    const int b  = rr / NA;
    const int ii = rr - b * NA;
    const float* m0 = mu + (size_t)b * (NA + 1) * (NB + 1)
                         + (size_t)ii * (NB + 1) + jj;     // mu[b][ii][jj..jj+4]
    const float* m1 = m0 + (NB + 1);                       // mu[b][ii+1][jj..jj+4]
    const float d0 = m0[0], d1 = m0[1], d2 = m0[2], d3 = m0[3], d4 = m0[4];
    const float L0 = m1[0], L1 = m1[1], L2 = m1[2], L3 = m1[3], L4 = m1[4];
    const f4 wv = *(const f4*)(W + idx);
    const f4 mk = *(const f4*)(mask + idx);

    const float t0 = wv.x - L1, t1 = wv.y - L2, t2 = wv.z - L3, t3 = wv.w - L4;
    f4 o0, o1, o2;
    o0.x = exp2f((d1 + t0) * LOG2E) * mk.x;   // c0 up
    o0.y = exp2f((L0 + t0) * LOG2E) * mk.x;   // c0 left
    o0.z = exp2f((d0 + t0) * LOG2E) * mk.x;   // c0 diag
    o0.w = exp2f((d2 + t1) * LOG2E) * mk.y;   // c1 up
    o1.x = exp2f((L1 + t1) * LOG2E) * mk.y;   // c1 left
    o1.y = exp2f((d1 + t1) * LOG2E) * mk.y;   // c1 diag
    o1.z = exp2f((d3 + t2) * LOG2E) * mk.z;   // c2 up
    o1.w = exp2f((L2 + t2) * LOG2E) * mk.z;   // c2 left
    o2.x = exp2f((d2 + t2) * LOG2E) * mk.z;   // c2 diag
    o2.y = exp2f((d4 + t3) * LOG2E) * mk.w;   // c3 up
    o2.z = exp2f((L3 + t3) * LOG2E) * mk.w;   // c3 left
    o2.w = exp2f((d3 + t3) * LOG2E) * mk.w;   // c3 diag

    f4* po = (f4*)(pi + idx * 3);             // 48B-aligned
    po[0] = o0; po[1] = o1; po[2] = o2;
}

extern "C" void kernel_launch(void* const* d_in, const int* in_sizes, int n_in,
                              void* d_out, int out_size, void* d_ws, size_t ws_size,
                              hipStream_t stream) {
    const float* W    = (const float*)d_in[0];
    const float* mask = (const float*)d_in[1];
    float* mu = (float*)d_out;
    float* pi = mu + (size_t)NBATCH * (NA + 1) * (NB + 1);

    hipLaunchKernelGGL(dtw_mu, dim3(NBATCH), dim3(768), 0, stream, W, mu);

    const int cells  = NBATCH * NA * NB;              // 9437184
    const int blocks = cells / (256 * 4);             // 9216
    hipLaunchKernelGGL(dtw_pi, dim3(blocks), dim3(256), 0, stream,
                       W, mask, mu, pi);
}